// Round 1
// baseline (360.304 us; speedup 1.0000x reference)
//
#include <hip/hip_runtime.h>

// LSTMNet: SEQ=600, B=4096, IN=6, H=30, OUT=61, fp32 throughout.
// One lane per hidden unit (30 active lanes per batch element, 2 elements/wave).
// Weights live in registers; h broadcast via a 32-float LDS row per element.
// All cross-lane sharing is intra-wave -> no block barriers, only lgkmcnt fences.

#define SEQ   600
#define BATCH 4096
#define INP   6
#define HID   30
#define NOUT  61
#define EPB   8   // batch elements per 256-thread block (tid>>5)

__device__ __forceinline__ float rcp_(float x) { return __builtin_amdgcn_rcpf(x); }
__device__ __forceinline__ float sigm_(float x) { return rcp_(1.0f + __expf(-x)); }
__device__ __forceinline__ float tanh_(float x) {
    // tanh(x) = 1 - 2/(exp(2x)+1); saturates correctly at +/-inf.
    float e = __expf(2.0f * x);
    return 1.0f - 2.0f * rcp_(e + 1.0f);
}

extern "C" __global__ void __launch_bounds__(256, 2)
lstm_fused(const float* __restrict__ X,   const float* __restrict__ Wih,
           const float* __restrict__ Whh, const float* __restrict__ bih,
           const float* __restrict__ bhh, const float* __restrict__ W1,
           const float* __restrict__ b1,  const float* __restrict__ W2,
           const float* __restrict__ b2,  float* __restrict__ out)
{
    __shared__ float h_sh[EPB][32];   // per-element h broadcast row (pads stay 0/garbage*0)
    __shared__ float o1_sh[EPB][32];  // fc1 activations

    const int tid  = threadIdx.x;
    const int u    = tid & 31;        // hidden unit (30 active)
    const int e    = tid >> 5;        // element slot within block, 0..7
    const int b    = blockIdx.x * EPB + e;
    const bool act = (u < HID);

    h_sh[e][u] = 0.0f;

    // ---- per-lane weights in registers (zero-padded to 32 for float4 h reads) ----
    float wi[32], wf[32], wg[32], wo[32];
    float vi[INP], vf[INP], vg[INP], vo[INP];
    float bi = 0.f, bf = 0.f, bg = 0.f, bo = 0.f;
    #pragma unroll
    for (int k = 0; k < 32; ++k) { wi[k] = 0.f; wf[k] = 0.f; wg[k] = 0.f; wo[k] = 0.f; }
    #pragma unroll
    for (int k = 0; k < INP; ++k) { vi[k] = 0.f; vf[k] = 0.f; vg[k] = 0.f; vo[k] = 0.f; }

    if (act) {
        #pragma unroll
        for (int k = 0; k < HID; ++k) {
            wi[k] = Whh[(0 * HID + u) * HID + k];
            wf[k] = Whh[(1 * HID + u) * HID + k];
            wg[k] = Whh[(2 * HID + u) * HID + k];
            wo[k] = Whh[(3 * HID + u) * HID + k];
        }
        #pragma unroll
        for (int k = 0; k < INP; ++k) {
            vi[k] = Wih[(0 * HID + u) * INP + k];
            vf[k] = Wih[(1 * HID + u) * INP + k];
            vg[k] = Wih[(2 * HID + u) * INP + k];
            vo[k] = Wih[(3 * HID + u) * INP + k];
        }
        bi = bih[0 * HID + u] + bhh[0 * HID + u];
        bf = bih[1 * HID + u] + bhh[1 * HID + u];
        bg = bih[2 * HID + u] + bhh[2 * HID + u];
        bo = bih[3 * HID + u] + bhh[3 * HID + u];
    }

    float c = 0.f, h = 0.f;
    float x[INP], xn[INP] = {};
    {
        const float* p = X + (size_t)b * INP;   // t = 0
        #pragma unroll
        for (int k = 0; k < INP; ++k) x[k] = p[k];
    }
    // make the zero-init of h_sh visible to this wave's reads
    asm volatile("s_waitcnt lgkmcnt(0)" ::: "memory");

    const float4* h4p = (const float4*)(&h_sh[e][0]);

    for (int t = 0; t < SEQ; ++t) {
        // prefetch X for t+1 (latency hides under this step's compute)
        if (t + 1 < SEQ) {
            const float* p = X + ((size_t)(t + 1) * BATCH + b) * INP;
            #pragma unroll
            for (int k = 0; k < INP; ++k) xn[k] = p[k];
        }

        float ai = bi, af = bf, ag = bg, ao = bo;
        #pragma unroll
        for (int k = 0; k < INP; ++k) {
            ai = fmaf(vi[k], x[k], ai);
            af = fmaf(vf[k], x[k], af);
            ag = fmaf(vg[k], x[k], ag);
            ao = fmaf(vo[k], x[k], ao);
        }
        #pragma unroll
        for (int q = 0; q < 8; ++q) {
            float4 hv = h4p[q];
            ai = fmaf(wi[4*q+0], hv.x, ai); af = fmaf(wf[4*q+0], hv.x, af);
            ag = fmaf(wg[4*q+0], hv.x, ag); ao = fmaf(wo[4*q+0], hv.x, ao);
            ai = fmaf(wi[4*q+1], hv.y, ai); af = fmaf(wf[4*q+1], hv.y, af);
            ag = fmaf(wg[4*q+1], hv.y, ag); ao = fmaf(wo[4*q+1], hv.y, ao);
            ai = fmaf(wi[4*q+2], hv.z, ai); af = fmaf(wf[4*q+2], hv.z, af);
            ag = fmaf(wg[4*q+2], hv.z, ag); ao = fmaf(wo[4*q+2], hv.z, ao);
            ai = fmaf(wi[4*q+3], hv.w, ai); af = fmaf(wf[4*q+3], hv.w, af);
            ag = fmaf(wg[4*q+3], hv.w, ag); ao = fmaf(wo[4*q+3], hv.w, ao);
        }

        float gi = sigm_(ai);
        float gf = sigm_(af);
        float go = sigm_(ao);
        float gg = tanh_(ag);
        c = gf * c + gi * gg;
        h = go * tanh_(c);
        // inactive lanes: all-zero weights/biases -> gg=0, c=0, h=0 forever.

        h_sh[e][u] = h;
        // intra-wave LDS RAW: DS ops complete in order per wave; fence stops
        // compiler reordering and drains before next iter's ds_reads.
        asm volatile("s_waitcnt lgkmcnt(0)" ::: "memory");

        #pragma unroll
        for (int k = 0; k < INP; ++k) x[k] = xn[k];
    }

    // ---- FC1: o1[u] = b1[u] + sum_k W1[u,k] * h[k] ----
    if (act) {
        float a1 = b1[u];
        const float* w1r = W1 + u * HID;
        #pragma unroll
        for (int k = 0; k < HID; ++k) a1 = fmaf(w1r[k], h_sh[e][k], a1);
        o1_sh[e][u] = a1;
    }
    asm volatile("s_waitcnt lgkmcnt(0)" ::: "memory");

    // ---- FC2: out[o] = b2[o] + sum_j W2[o,j] * o1[j] ----
    if (act) {
        for (int o = u; o < NOUT; o += HID) {   // u=0 -> {0,30,60}, u>0 -> {u, u+30}
            float a2 = b2[o];
            const float* w2r = W2 + o * HID;
            #pragma unroll
            for (int k = 0; k < HID; ++k) a2 = fmaf(w2r[k], o1_sh[e][k], a2);
            out[(size_t)b * NOUT + o] = a2;
        }
    }
}

extern "C" void kernel_launch(void* const* d_in, const int* in_sizes, int n_in,
                              void* d_out, int out_size, void* d_ws, size_t ws_size,
                              hipStream_t stream) {
    const float* X   = (const float*)d_in[0];
    const float* Wih = (const float*)d_in[1];
    const float* Whh = (const float*)d_in[2];
    const float* bih = (const float*)d_in[3];
    const float* bhh = (const float*)d_in[4];
    const float* W1  = (const float*)d_in[5];
    const float* b1  = (const float*)d_in[6];
    const float* W2  = (const float*)d_in[7];
    const float* b2  = (const float*)d_in[8];
    float* out = (float*)d_out;

    dim3 grid(BATCH / EPB);   // 512 blocks
    dim3 block(256);          // 4 waves, 8 elements
    hipLaunchKernelGGL(lstm_fused, grid, block, 0, stream,
                       X, Wih, Whh, bih, bhh, W1, b1, W2, b2, out);
}